// Round 2
// baseline (5508.080 us; speedup 1.0000x reference)
//
#include <hip/hip_runtime.h>
#include <stdint.h>
#include <stddef.h>

#define D_MODEL 1024
#define NH 16
#define DKH 64
#define SEQ 2048
#define BATCH 4
#define LAYERS 6
#define DFF_N 4096
#define MROWS (BATCH*SEQ)   // 8192 token rows

typedef __attribute__((ext_vector_type(8))) __bf16 bf16x8;
typedef __attribute__((ext_vector_type(4))) float f32x4;
typedef unsigned int uint4a __attribute__((ext_vector_type(4), may_alias, aligned(16)));
typedef __attribute__((ext_vector_type(4))) unsigned short u16x4;

__device__ __forceinline__ unsigned short f2b(float f) {
  union { float f; uint32_t u; } x; x.f = f;
  uint32_t u = x.u + 0x7fffu + ((x.u >> 16) & 1u);   // RNE
  return (unsigned short)(u >> 16);
}

__device__ __forceinline__ uint32_t pk2(float lo, float hi) {
  return (uint32_t)f2b(lo) | ((uint32_t)f2b(hi) << 16);
}

__device__ __forceinline__ uint32_t shfl_u32(uint32_t v, int src) {
  return (uint32_t)__shfl((int)v, src, 64);
}

__device__ __forceinline__ bf16x8 ld8(const unsigned short* p) {
  return __builtin_bit_cast(bf16x8, *(const uint4a*)p);
}

__device__ __forceinline__ void gload_lds16(const unsigned short* g, unsigned short* l) {
  // async 16B/lane global->LDS; LDS dest = wave-uniform base + lane*16
  __builtin_amdgcn_global_load_lds((const __attribute__((address_space(1))) void*)g,
                                   (__attribute__((address_space(3))) void*)l, 16, 0, 0);
}

// ---------------------------------------------------------------- transpose+cvt
// dst[c][r] = bf16(src[r][c]); src is R x C f32. grid (C/32, R/32), block 256.
__global__ __launch_bounds__(256)
void transpose_cvt(const float* __restrict__ src, unsigned short* __restrict__ dst,
                   int R, int C)
{
  __shared__ float tile[32][33];
  int tx = threadIdx.x & 31, ty = threadIdx.x >> 5;        // 32 x 8
  int c0 = blockIdx.x * 32, r0 = blockIdx.y * 32;
#pragma unroll
  for (int i = 0; i < 4; i++)
    tile[ty + i*8][tx] = src[(size_t)(r0 + ty + i*8)*C + c0 + tx];
  __syncthreads();
#pragma unroll
  for (int i = 0; i < 4; i++)
    dst[(size_t)(c0 + ty + i*8)*R + r0 + tx] = f2b(tile[tx][ty + i*8]);
}

// ---------------------------------------------------------------- embed + PE
__global__ __launch_bounds__(256)
void embed_kernel(const int* __restrict__ x, const float* __restrict__ emb,
                  float* __restrict__ h, unsigned short* __restrict__ hb)
{
  size_t q = (size_t)blockIdx.x * 256 + threadIdx.x;       // over MROWS*D/4
  size_t e0 = q << 2;
  int d0 = (int)(e0 & (D_MODEL - 1));
  size_t bs = e0 >> 10;
  int s = (int)(bs & (SEQ - 1));
  int tok = x[bs];
  const float4 ev = *(const float4*)(emb + (size_t)tok * D_MODEL + d0);
  int i0 = d0 >> 1;
  float div0 = __expf(-0.017988946039016f * (float)i0);        // exp(2i*-ln(1e4)/1024)
  float div1 = __expf(-0.017988946039016f * (float)(i0 + 1));
  float a0 = (float)s * div0, a1 = (float)s * div1;
  float4 o;
  o.x = ev.x * 32.0f + __sinf(a0);                             // sqrt(1024)=32
  o.y = ev.y * 32.0f + __cosf(a0);
  o.z = ev.z * 32.0f + __sinf(a1);
  o.w = ev.w * 32.0f + __cosf(a1);
  *(float4*)(h + e0) = o;
  u16x4 ob = { f2b(o.x), f2b(o.y), f2b(o.z), f2b(o.w) };
  *(u16x4*)(hb + e0) = ob;
}

// ---------------------------------------------------------------- LayerNorm
__global__ __launch_bounds__(256)
void ln_kernel(const float* __restrict__ in, const float* __restrict__ g,
               const float* __restrict__ be, float* __restrict__ outf,
               unsigned short* __restrict__ outb)
{
  int row = blockIdx.x;
  int t = threadIdx.x, lane = t & 63, w = t >> 6;
  float4 v = *(const float4*)(in + (size_t)row * D_MODEL + t*4);
  float s = v.x + v.y + v.z + v.w;
#pragma unroll
  for (int off = 1; off < 64; off <<= 1) s += __shfl_xor(s, off);
  __shared__ float redA[4], redB[4];
  if (lane == 0) redA[w] = s;
  __syncthreads();
  float mu = (redA[0] + redA[1] + redA[2] + redA[3]) * (1.0f / D_MODEL);
  float dx = v.x - mu, dy = v.y - mu, dz = v.z - mu, dw = v.w - mu;
  float q = dx*dx + dy*dy + dz*dz + dw*dw;
#pragma unroll
  for (int off = 1; off < 64; off <<= 1) q += __shfl_xor(q, off);
  if (lane == 0) redB[w] = q;
  __syncthreads();
  float var = (redB[0] + redB[1] + redB[2] + redB[3]) * (1.0f / D_MODEL);
  float rs = rsqrtf(var + 1e-5f);
  float4 gv = *(const float4*)(g + t*4);
  float4 bv = *(const float4*)(be + t*4);
  float4 o;
  o.x = dx * rs * gv.x + bv.x;
  o.y = dy * rs * gv.y + bv.y;
  o.z = dz * rs * gv.z + bv.z;
  o.w = dw * rs * gv.w + bv.w;
  *(float4*)(outf + (size_t)row * D_MODEL + t*4) = o;
  if (outb) {
    u16x4 ob = { f2b(o.x), f2b(o.y), f2b(o.z), f2b(o.w) };
    *(u16x4*)(outb + (size_t)row * D_MODEL + t*4) = ob;
  }
}

// ---------------------------------------------------------------- GEMM (B^T form)
#define BM 128
#define BN 128
#define BKT 32

#define GM_QKV 0
#define GM_ADDRES 1
#define GM_RELU 2

template<int MODE>
__global__ __launch_bounds__(256)
void gemm_bt(const unsigned short* __restrict__ A,
             const unsigned short* __restrict__ Bt,
             const float* __restrict__ bias0, const float* __restrict__ bias1,
             const float* __restrict__ bias2, const float* __restrict__ resid,
             float* __restrict__ outf, unsigned short* __restrict__ outb,
             unsigned short* __restrict__ qo, unsigned short* __restrict__ ko,
             unsigned short* __restrict__ vo,
             int M, int N, int K)
{
  __shared__ __align__(16) unsigned short sA[BM * BKT];
  __shared__ __align__(16) unsigned short sB[BN * BKT];
  int tid = threadIdx.x;
  int w = tid >> 6, lane = tid & 63;
  int lm = lane & 15, lq = lane >> 4;
  int wm = w & 1, wn = w >> 1;

  // T1: XCD k (= orig%8) processes contiguous chunk of the grid
  int nwg  = gridDim.x * gridDim.y;
  int orig = blockIdx.y * gridDim.x + blockIdx.x;
  int nx   = nwg >> 3;
  int wg   = (orig & 7) * nx + (orig >> 3);
  int bx   = wg % gridDim.x, by = wg / gridDim.x;
  int n0 = bx * BN, m0 = by * BM;

  f32x4 acc[4][4];
#pragma unroll
  for (int i = 0; i < 4; i++)
#pragma unroll
    for (int j = 0; j < 4; j++) acc[i][j] = (f32x4){0.f, 0.f, 0.f, 0.f};

  int srow = lane >> 2;               // 0..15
  int scol = (lane & 3) * 8;          // element offset in K
  const unsigned short* ga0 = A  + (size_t)(m0 + w*32 + srow) * K + scol;
  const unsigned short* ga1 = ga0 + (size_t)16 * K;
  const unsigned short* gb0 = Bt + (size_t)(n0 + w*32 + srow) * K + scol;
  const unsigned short* gb1 = gb0 + (size_t)16 * K;
  unsigned short* la0 = &sA[(w*32 +  0) * BKT];
  unsigned short* la1 = &sA[(w*32 + 16) * BKT];
  unsigned short* lb0 = &sB[(w*32 +  0) * BKT];
  unsigned short* lb1 = &sB[(w*32 + 16) * BKT];

  for (int kt = 0; kt < K; kt += BKT) {
    gload_lds16(ga0 + kt, la0);
    gload_lds16(ga1 + kt, la1);
    gload_lds16(gb0 + kt, lb0);
    gload_lds16(gb1 + kt, lb1);
    __syncthreads();
    bf16x8 af[4], bfr[4];
#pragma unroll
    for (int i = 0; i < 4; i++)
      af[i] = ld8(&sA[(wm*64 + i*16 + lm) * BKT + lq*8]);
#pragma unroll
    for (int j = 0; j < 4; j++)
      bfr[j] = ld8(&sB[(wn*64 + j*16 + lm) * BKT + lq*8]);
#pragma unroll
    for (int i = 0; i < 4; i++)
#pragma unroll
      for (int j = 0; j < 4; j++)
        acc[i][j] = __builtin_amdgcn_mfma_f32_16x16x32_bf16(af[i], bfr[j], acc[i][j], 0, 0, 0);
    __syncthreads();
  }

  // epilogue: C row = (lane>>4)*4 + r, col = lane&15 (verified m89/m91)
#pragma unroll
  for (int i = 0; i < 4; i++) {
#pragma unroll
    for (int j = 0; j < 4; j++) {
      int n = n0 + wn*64 + j*16 + lm;
#pragma unroll
      for (int r = 0; r < 4; r++) {
        int m = m0 + wm*64 + i*16 + lq*4 + r;
        float val = acc[i][j][r];
        if constexpr (MODE == GM_QKV) {
          int which = n >> 10, nn = n & 1023;
          const float* bb = (which == 0) ? bias0 : (which == 1) ? bias1 : bias2;
          val += bb[nn];
          int hh = nn >> 6, dk = nn & 63;
          int b = m >> 11, s = m & 2047;
          size_t bh = (size_t)(b * NH + hh);
          if (which == 0)      qo[(bh * SEQ + s) * DKH + dk] = f2b(val);
          else if (which == 1) ko[(bh * SEQ + s) * DKH + dk] = f2b(val);
          else                 vo[(bh * DKH + dk) * SEQ + s] = f2b(val);   // V transposed
        } else if constexpr (MODE == GM_ADDRES) {
          val += bias0[n] + resid[(size_t)m * N + n];
          outf[(size_t)m * N + n] = val;
        } else {  // GM_RELU
          val += bias0[n];
          val = fmaxf(val, 0.f);
          outb[(size_t)m * N + n] = f2b(val);
        }
      }
    }
  }
}

// ---------------------------------------------------------------- flash attention
// Swapped-operand structure: per wave 16 q rows, 32 keys/step.
//   QK^T: S^T = mfma(A=K_frag, B=Q_frag). A/B frag layouts coincide for
//   16x16x32 (row/col=lane&15, k=(lane>>4)*8+e), so the SAME loads as the
//   q-major orientation are used; only operand order differs. Output
//   (C layout col=lane&15, row=(lane>>4)*4+r): lane (lm,lq) holds
//   S[kt + lq*4 + r][q0+lm] in s0 and S[kt+16+lq*4+r][q0+lm] in s1
//   -> softmax state (mi, li) is per-lane SCALAR; row-max/sum = 7 in-lane
//   ops + 2 shfl_xor (16,32) instead of 4x(4-step) shfl chains.
//   PV: O^T = mfma(A=V^T_frag, B=P_frag). V^T loads identical to before.
//   P_frag (lane needs P[lm][lq*8..+7]) built by 8 __shfl + 4 selects from
//   the packed bf16 pairs (no LDS round-trip, no bank conflicts):
//     w0=(k=lq*4+0,1) w1=(+2,3) w2=(16+lq*4+0,1) w3=(+2,3)
//     bw[e] <- word ((lq<2?0:2)+(e&1)) of lane lm+(2*(lq&1)+(e>>1))*16.
//   Output: o[jt][r] = O[q0+lm][jt*16+lq*4+r] -> contiguous u16x4 stores.
__global__ __launch_bounds__(256)
void attn_kernel(const unsigned short* __restrict__ qb,
                 const unsigned short* __restrict__ kb,
                 const unsigned short* __restrict__ vtb,
                 const int* __restrict__ mask,
                 unsigned short* __restrict__ ctx)
{
  int lane = threadIdx.x & 63, w = threadIdx.x >> 6;
  int lm = lane & 15, lq = lane >> 4;
  int nqb = SEQ / 64;
  int qbi = blockIdx.x % nqb;
  int bh  = blockIdx.x / nqb;
  int b = bh / NH, hh = bh % NH;
  int q0 = qbi * 64 + w * 16;
  const unsigned short* qp = qb  + (size_t)bh * SEQ * DKH;
  const unsigned short* kp = kb  + (size_t)bh * SEQ * DKH;
  const unsigned short* vp = vtb + (size_t)bh * DKH * SEQ;
  const int* mp = mask + (size_t)b * SEQ;

  bf16x8 aq0 = ld8(qp + (q0 + lm) * DKH + lq*8);
  bf16x8 aq1 = ld8(qp + (q0 + lm) * DKH + lq*8 + 32);

  f32x4 o[4];
#pragma unroll
  for (int j = 0; j < 4; j++) o[j] = (f32x4){0.f, 0.f, 0.f, 0.f};
  float mi = -1e30f, li = 0.f;
  const float scale = 0.125f;   // 1/sqrt(64)

  for (int kt = 0; kt < SEQ; kt += 32) {
    bf16x8 bk00 = ld8(kp + (kt      + lm) * DKH + lq*8);
    bf16x8 bk01 = ld8(kp + (kt      + lm) * DKH + lq*8 + 32);
    bf16x8 bk10 = ld8(kp + (kt + 16 + lm) * DKH + lq*8);
    bf16x8 bk11 = ld8(kp + (kt + 16 + lm) * DKH + lq*8 + 32);
    f32x4 s0 = (f32x4){0.f,0.f,0.f,0.f}, s1 = (f32x4){0.f,0.f,0.f,0.f};
    s0 = __builtin_amdgcn_mfma_f32_16x16x32_bf16(bk00, aq0, s0, 0, 0, 0);
    s0 = __builtin_amdgcn_mfma_f32_16x16x32_bf16(bk01, aq1, s0, 0, 0, 0);
    s1 = __builtin_amdgcn_mfma_f32_16x16x32_bf16(bk10, aq0, s1, 0, 0, 0);
    s1 = __builtin_amdgcn_mfma_f32_16x16x32_bf16(bk11, aq1, s1, 0, 0, 0);

    int4 m0v = *(const int4*)(mp + kt + lq*4);
    int4 m1v = *(const int4*)(mp + kt + 16 + lq*4);
    int m0a[4] = { m0v.x, m0v.y, m0v.z, m0v.w };
    int m1a[4] = { m1v.x, m1v.y, m1v.z, m1v.w };
    float sv0[4], sv1[4];
#pragma unroll
    for (int r = 0; r < 4; r++) {
      sv0[r] = m0a[r] ? s0[r] * scale : -1e9f;
      sv1[r] = m1a[r] ? s1[r] * scale : -1e9f;
    }
    // row max over this 32-key block (per q = lm)
    float mt = fmaxf(fmaxf(fmaxf(sv0[0], sv0[1]), fmaxf(sv0[2], sv0[3])),
                     fmaxf(fmaxf(sv1[0], sv1[1]), fmaxf(sv1[2], sv1[3])));
    mt = fmaxf(mt, __shfl_xor(mt, 16));
    mt = fmaxf(mt, __shfl_xor(mt, 32));
    // T13 defer-max: rescale only when block max pushes past mi + 8
    if (__any(mt - mi > 8.0f)) {
      float mn = fmaxf(mi, mt);
      float al = __expf(mi - mn);
      mi = mn;
      li *= al;
#pragma unroll
      for (int jt = 0; jt < 4; jt++)
#pragma unroll
        for (int r = 0; r < 4; r++) o[jt][r] *= al;
    }
    float p0[4], p1[4];
#pragma unroll
    for (int r = 0; r < 4; r++) {
      p0[r] = __expf(sv0[r] - mi);
      p1[r] = __expf(sv1[r] - mi);
    }
    float ls = (p0[0] + p0[1]) + (p0[2] + p0[3]) + (p1[0] + p1[1]) + (p1[2] + p1[3]);
    ls += __shfl_xor(ls, 16);
    ls += __shfl_xor(ls, 32);
    li += ls;
    // pack and exchange P into B-fragment layout (lane needs P[lm][lq*8..+7])
    uint32_t w0 = pk2(p0[0], p0[1]);
    uint32_t w1 = pk2(p0[2], p0[3]);
    uint32_t w2 = pk2(p1[0], p1[1]);
    uint32_t w3 = pk2(p1[2], p1[3]);
    uint4a pw4;
#pragma unroll
    for (int e = 0; e < 4; e++) {
      int src = lm + (2*(lq & 1) + (e >> 1)) * 16;
      uint32_t tlo = shfl_u32((e & 1) ? w1 : w0, src);
      uint32_t thi = shfl_u32((e & 1) ? w3 : w2, src);
      pw4[e] = (lq < 2) ? tlo : thi;
    }
    bf16x8 pfrag = __builtin_bit_cast(bf16x8, pw4);
#pragma unroll
    for (int jt = 0; jt < 4; jt++) {
      bf16x8 bv = ld8(vp + (jt*16 + lm) * SEQ + kt + lq*8);
      o[jt] = __builtin_amdgcn_mfma_f32_16x16x32_bf16(bv, pfrag, o[jt], 0, 0, 0);
    }
  }
  float inv = 1.0f / li;
#pragma unroll
  for (int jt = 0; jt < 4; jt++) {
    u16x4 ov;
#pragma unroll
    for (int r = 0; r < 4; r++) ov[r] = f2b(o[jt][r] * inv);
    *(u16x4*)(ctx + (size_t)(b * SEQ + q0 + lm) * D_MODEL + hh*DKH + jt*16 + lq*4) = ov;
  }
}

// ---------------------------------------------------------------- launcher
extern "C" void kernel_launch(void* const* d_in, const int* in_sizes, int n_in,
                              void* d_out, int out_size, void* d_ws, size_t ws_size,
                              hipStream_t stream) {
  const int*   x    = (const int*)d_in[0];
  const int*   mask = (const int*)d_in[1];
  const float* emb  = (const float*)d_in[2];
  const float* wq   = (const float*)d_in[3];
  const float* bq   = (const float*)d_in[4];
  const float* wk   = (const float*)d_in[5];
  const float* bk   = (const float*)d_in[6];
  const float* wv   = (const float*)d_in[7];
  const float* bv   = (const float*)d_in[8];
  const float* wo   = (const float*)d_in[9];
  const float* bo   = (const float*)d_in[10];
  const float* w1   = (const float*)d_in[11];
  const float* b1   = (const float*)d_in[12];
  const float* w2   = (const float*)d_in[13];
  const float* b2   = (const float*)d_in[14];
  const float* g1   = (const float*)d_in[15];
  const float* be1  = (const float*)d_in[16];
  const float* g2   = (const float*)d_in[17];
  const float* be2  = (const float*)d_in[18];
  const float* gf   = (const float*)d_in[19];
  const float* bfin = (const float*)d_in[20];

  const size_t DD = (size_t)D_MODEL * D_MODEL;       // 1M
  const size_t DDF = (size_t)D_MODEL * DFF_N;        // 4M
  char* p = (char*)d_ws;
  auto alloc = [&](size_t bytes) { void* r = (void*)p; p += (bytes + 255) & ~(size_t)255; return r; };
  unsigned short* qkvT = (unsigned short*)alloc(LAYERS * 3 * DD * 2);
  unsigned short* woT  = (unsigned short*)alloc(LAYERS * DD * 2);
  unsigned short* w1T  = (unsigned short*)alloc(LAYERS * DDF * 2);
  unsigned short* w2T  = (unsigned short*)alloc(LAYERS * DDF * 2);
  float*          h    = (float*)alloc((size_t)MROWS * D_MODEL * 4);
  unsigned short* hb   = (unsigned short*)alloc((size_t)MROWS * D_MODEL * 2);
  float*          t0   = (float*)alloc((size_t)MROWS * D_MODEL * 4);
  unsigned short* qB   = (unsigned short*)alloc((size_t)MROWS * D_MODEL * 2);
  unsigned short* kB   = (unsigned short*)alloc((size_t)MROWS * D_MODEL * 2);
  unsigned short* vB   = (unsigned short*)alloc((size_t)MROWS * D_MODEL * 2);
  unsigned short* ctx  = (unsigned short*)alloc((size_t)MROWS * D_MODEL * 2);
  unsigned short* ffa  = qB;   // lifetime-disjoint: reuse q/k/v/ctx region (64MB)

  // ---- weight prep (every call: ws is re-poisoned) ----
  for (int l = 0; l < LAYERS; l++) {
    transpose_cvt<<<dim3(32, 32), 256, 0, stream>>>(wq + l*DD, qkvT + l*3*DD,          D_MODEL, D_MODEL);
    transpose_cvt<<<dim3(32, 32), 256, 0, stream>>>(wk + l*DD, qkvT + l*3*DD + DD,     D_MODEL, D_MODEL);
    transpose_cvt<<<dim3(32, 32), 256, 0, stream>>>(wv + l*DD, qkvT + l*3*DD + 2*DD,   D_MODEL, D_MODEL);
    transpose_cvt<<<dim3(32, 32), 256, 0, stream>>>(wo + l*DD, woT + l*DD,             D_MODEL, D_MODEL);
    transpose_cvt<<<dim3(DFF_N/32, D_MODEL/32), 256, 0, stream>>>(w1 + l*DDF, w1T + l*DDF, D_MODEL, DFF_N);
    transpose_cvt<<<dim3(D_MODEL/32, DFF_N/32), 256, 0, stream>>>(w2 + l*DDF, w2T + l*DDF, DFF_N, D_MODEL);
  }

  embed_kernel<<<MROWS * D_MODEL / 1024, 256, 0, stream>>>(x, emb, h, hb);

  for (int l = 0; l < LAYERS; l++) {
    gemm_bt<GM_QKV><<<dim3(3072/BN, MROWS/BM), 256, 0, stream>>>(
        hb, qkvT + l*3*DD, bq + l*D_MODEL, bk + l*D_MODEL, bv + l*D_MODEL,
        nullptr, nullptr, nullptr, qB, kB, vB, MROWS, 3072, D_MODEL);
    attn_kernel<<<BATCH*NH*(SEQ/64), 256, 0, stream>>>(qB, kB, vB, mask, ctx);
    gemm_bt<GM_ADDRES><<<dim3(D_MODEL/BN, MROWS/BM), 256, 0, stream>>>(
        ctx, woT + l*DD, bo + l*D_MODEL, nullptr, nullptr, h,
        t0, nullptr, nullptr, nullptr, nullptr, MROWS, D_MODEL, D_MODEL);
    ln_kernel<<<MROWS, 256, 0, stream>>>(t0, g1 + l*D_MODEL, be1 + l*D_MODEL, h, hb);
    gemm_bt<GM_RELU><<<dim3(DFF_N/BN, MROWS/BM), 256, 0, stream>>>(
        hb, w1T + l*DDF, b1 + l*DFF_N, nullptr, nullptr, nullptr,
        nullptr, ffa, nullptr, nullptr, nullptr, MROWS, DFF_N, D_MODEL);
    gemm_bt<GM_ADDRES><<<dim3(D_MODEL/BN, MROWS/BM), 256, 0, stream>>>(
        ffa, w2T + l*DDF, b2 + l*D_MODEL, nullptr, nullptr, h,
        t0, nullptr, nullptr, nullptr, nullptr, MROWS, D_MODEL, DFF_N);
    ln_kernel<<<MROWS, 256, 0, stream>>>(t0, g2 + l*D_MODEL, be2 + l*D_MODEL, h, hb);
  }

  ln_kernel<<<MROWS, 256, 0, stream>>>(h, gf, bfin, (float*)d_out, nullptr);
}

// Round 4
// 5501.820 us; speedup vs baseline: 1.0011x; 1.0011x over previous
//
#include <hip/hip_runtime.h>
#include <stdint.h>
#include <stddef.h>

#define D_MODEL 1024
#define NH 16
#define DKH 64
#define SEQ 2048
#define BATCH 4
#define LAYERS 6
#define DFF_N 4096
#define MROWS (BATCH*SEQ)   // 8192 token rows

typedef __attribute__((ext_vector_type(8))) __bf16 bf16x8;
typedef __attribute__((ext_vector_type(4))) float f32x4;
typedef unsigned int uint4a __attribute__((ext_vector_type(4), may_alias, aligned(16)));
typedef __attribute__((ext_vector_type(4))) unsigned short u16x4;

__device__ __forceinline__ unsigned short f2b(float f) {
  union { float f; uint32_t u; } x; x.f = f;
  uint32_t u = x.u + 0x7fffu + ((x.u >> 16) & 1u);   // RNE
  return (unsigned short)(u >> 16);
}

__device__ __forceinline__ uint32_t pk2(float lo, float hi) {
  return (uint32_t)f2b(lo) | ((uint32_t)f2b(hi) << 16);
}

__device__ __forceinline__ uint32_t shfl_u32(uint32_t v, int src) {
  return (uint32_t)__shfl((int)v, src, 64);
}

__device__ __forceinline__ bf16x8 ld8(const unsigned short* p) {
  return __builtin_bit_cast(bf16x8, *(const uint4a*)p);
}

__device__ __forceinline__ void gload_lds16(const unsigned short* g, unsigned short* l) {
  // async 16B/lane global->LDS; LDS dest = wave-uniform base + lane*16
  __builtin_amdgcn_global_load_lds((const __attribute__((address_space(1))) void*)g,
                                   (__attribute__((address_space(3))) void*)l, 16, 0, 0);
}

// ---------------------------------------------------------------- transpose+cvt
// dst[c][r] = bf16(src[r][c]); src is R x C f32. grid (C/32, R/32), block 256.
__global__ __launch_bounds__(256)
void transpose_cvt(const float* __restrict__ src, unsigned short* __restrict__ dst,
                   int R, int C)
{
  __shared__ float tile[32][33];
  int tx = threadIdx.x & 31, ty = threadIdx.x >> 5;        // 32 x 8
  int c0 = blockIdx.x * 32, r0 = blockIdx.y * 32;
#pragma unroll
  for (int i = 0; i < 4; i++)
    tile[ty + i*8][tx] = src[(size_t)(r0 + ty + i*8)*C + c0 + tx];
  __syncthreads();
#pragma unroll
  for (int i = 0; i < 4; i++)
    dst[(size_t)(c0 + ty + i*8)*R + r0 + tx] = f2b(tile[tx][ty + i*8]);
}

// ---------------------------------------------------------------- embed + PE
__global__ __launch_bounds__(256)
void embed_kernel(const int* __restrict__ x, const float* __restrict__ emb,
                  float* __restrict__ h, unsigned short* __restrict__ hb)
{
  size_t q = (size_t)blockIdx.x * 256 + threadIdx.x;       // over MROWS*D/4
  size_t e0 = q << 2;
  int d0 = (int)(e0 & (D_MODEL - 1));
  size_t bs = e0 >> 10;
  int s = (int)(bs & (SEQ - 1));
  int tok = x[bs];
  const float4 ev = *(const float4*)(emb + (size_t)tok * D_MODEL + d0);
  int i0 = d0 >> 1;
  float div0 = __expf(-0.017988946039016f * (float)i0);        // exp(2i*-ln(1e4)/1024)
  float div1 = __expf(-0.017988946039016f * (float)(i0 + 1));
  float a0 = (float)s * div0, a1 = (float)s * div1;
  float4 o;
  o.x = ev.x * 32.0f + __sinf(a0);                             // sqrt(1024)=32
  o.y = ev.y * 32.0f + __cosf(a0);
  o.z = ev.z * 32.0f + __sinf(a1);
  o.w = ev.w * 32.0f + __cosf(a1);
  *(float4*)(h + e0) = o;
  u16x4 ob = { f2b(o.x), f2b(o.y), f2b(o.z), f2b(o.w) };
  *(u16x4*)(hb + e0) = ob;
}

// ---------------------------------------------------------------- LayerNorm
__global__ __launch_bounds__(256)
void ln_kernel(const float* __restrict__ in, const float* __restrict__ g,
               const float* __restrict__ be, float* __restrict__ outf,
               unsigned short* __restrict__ outb)
{
  int row = blockIdx.x;
  int t = threadIdx.x, lane = t & 63, w = t >> 6;
  float4 v = *(const float4*)(in + (size_t)row * D_MODEL + t*4);
  float s = v.x + v.y + v.z + v.w;
#pragma unroll
  for (int off = 1; off < 64; off <<= 1) s += __shfl_xor(s, off);
  __shared__ float redA[4], redB[4];
  if (lane == 0) redA[w] = s;
  __syncthreads();
  float mu = (redA[0] + redA[1] + redA[2] + redA[3]) * (1.0f / D_MODEL);
  float dx = v.x - mu, dy = v.y - mu, dz = v.z - mu, dw = v.w - mu;
  float q = dx*dx + dy*dy + dz*dz + dw*dw;
#pragma unroll
  for (int off = 1; off < 64; off <<= 1) q += __shfl_xor(q, off);
  if (lane == 0) redB[w] = q;
  __syncthreads();
  float var = (redB[0] + redB[1] + redB[2] + redB[3]) * (1.0f / D_MODEL);
  float rs = rsqrtf(var + 1e-5f);
  float4 gv = *(const float4*)(g + t*4);
  float4 bv = *(const float4*)(be + t*4);
  float4 o;
  o.x = dx * rs * gv.x + bv.x;
  o.y = dy * rs * gv.y + bv.y;
  o.z = dz * rs * gv.z + bv.z;
  o.w = dw * rs * gv.w + bv.w;
  *(float4*)(outf + (size_t)row * D_MODEL + t*4) = o;
  if (outb) {
    u16x4 ob = { f2b(o.x), f2b(o.y), f2b(o.z), f2b(o.w) };
    *(u16x4*)(outb + (size_t)row * D_MODEL + t*4) = ob;
  }
}

// ---------------------------------------------------------------- GEMM (B^T form)
#define BM 128
#define BN 128
#define BKT 32

#define GM_QKV 0
#define GM_ADDRES 1
#define GM_RELU 2

template<int MODE>
__global__ __launch_bounds__(256)
void gemm_bt(const unsigned short* __restrict__ A,
             const unsigned short* __restrict__ Bt,
             const float* __restrict__ bias0, const float* __restrict__ bias1,
             const float* __restrict__ bias2, const float* __restrict__ resid,
             float* __restrict__ outf, unsigned short* __restrict__ outb,
             unsigned short* __restrict__ qo, unsigned short* __restrict__ ko,
             unsigned short* __restrict__ vo,
             int M, int N, int K)
{
  __shared__ __align__(16) unsigned short sA[BM * BKT];
  __shared__ __align__(16) unsigned short sB[BN * BKT];
  int tid = threadIdx.x;
  int w = tid >> 6, lane = tid & 63;
  int lm = lane & 15, lq = lane >> 4;
  int wm = w & 1, wn = w >> 1;

  // T1: XCD k (= orig%8) processes contiguous chunk of the grid
  int nwg  = gridDim.x * gridDim.y;
  int orig = blockIdx.y * gridDim.x + blockIdx.x;
  int nx   = nwg >> 3;
  int wg   = (orig & 7) * nx + (orig >> 3);
  int bx   = wg % gridDim.x, by = wg / gridDim.x;
  int n0 = bx * BN, m0 = by * BM;

  f32x4 acc[4][4];
#pragma unroll
  for (int i = 0; i < 4; i++)
#pragma unroll
    for (int j = 0; j < 4; j++) acc[i][j] = (f32x4){0.f, 0.f, 0.f, 0.f};

  int srow = lane >> 2;               // 0..15
  int scol = (lane & 3) * 8;          // element offset in K
  const unsigned short* ga0 = A  + (size_t)(m0 + w*32 + srow) * K + scol;
  const unsigned short* ga1 = ga0 + (size_t)16 * K;
  const unsigned short* gb0 = Bt + (size_t)(n0 + w*32 + srow) * K + scol;
  const unsigned short* gb1 = gb0 + (size_t)16 * K;
  unsigned short* la0 = &sA[(w*32 +  0) * BKT];
  unsigned short* la1 = &sA[(w*32 + 16) * BKT];
  unsigned short* lb0 = &sB[(w*32 +  0) * BKT];
  unsigned short* lb1 = &sB[(w*32 + 16) * BKT];

  for (int kt = 0; kt < K; kt += BKT) {
    gload_lds16(ga0 + kt, la0);
    gload_lds16(ga1 + kt, la1);
    gload_lds16(gb0 + kt, lb0);
    gload_lds16(gb1 + kt, lb1);
    __syncthreads();
    bf16x8 af[4], bfr[4];
#pragma unroll
    for (int i = 0; i < 4; i++)
      af[i] = ld8(&sA[(wm*64 + i*16 + lm) * BKT + lq*8]);
#pragma unroll
    for (int j = 0; j < 4; j++)
      bfr[j] = ld8(&sB[(wn*64 + j*16 + lm) * BKT + lq*8]);
#pragma unroll
    for (int i = 0; i < 4; i++)
#pragma unroll
      for (int j = 0; j < 4; j++)
        acc[i][j] = __builtin_amdgcn_mfma_f32_16x16x32_bf16(af[i], bfr[j], acc[i][j], 0, 0, 0);
    __syncthreads();
  }

  // epilogue: C row = (lane>>4)*4 + r, col = lane&15 (verified m89/m91)
#pragma unroll
  for (int i = 0; i < 4; i++) {
#pragma unroll
    for (int j = 0; j < 4; j++) {
      int n = n0 + wn*64 + j*16 + lm;
#pragma unroll
      for (int r = 0; r < 4; r++) {
        int m = m0 + wm*64 + i*16 + lq*4 + r;
        float val = acc[i][j][r];
        if constexpr (MODE == GM_QKV) {
          int which = n >> 10, nn = n & 1023;
          const float* bb = (which == 0) ? bias0 : (which == 1) ? bias1 : bias2;
          val += bb[nn];
          int hh = nn >> 6, dk = nn & 63;
          int b = m >> 11, s = m & 2047;
          size_t bh = (size_t)(b * NH + hh);
          if (which == 0)      qo[(bh * SEQ + s) * DKH + dk] = f2b(val);
          else if (which == 1) ko[(bh * SEQ + s) * DKH + dk] = f2b(val);
          else                 vo[(bh * DKH + dk) * SEQ + s] = f2b(val);   // V transposed
        } else if constexpr (MODE == GM_ADDRES) {
          val += bias0[n] + resid[(size_t)m * N + n];
          outf[(size_t)m * N + n] = val;
        } else {  // GM_RELU
          val += bias0[n];
          val = fmaxf(val, 0.f);
          outb[(size_t)m * N + n] = f2b(val);
        }
      }
    }
  }
}

// ---------------------------------------------------------------- flash attention
// Latency-optimized swapped-operand structure (see round-2 notes):
//  - S^T = mfma(K,Q); per-lane scalar softmax state (q-row = lm).
//  - K prefetched one full 32-key step ahead into registers (A/B named
//    buffers, manual unroll-2 -> all indices static, no scratch).
//  - V loads issued at step top, consumed after softmax (latency hidden).
//  - li: per-lane partial, reduced ONCE after the loop (2 shfl total).
//  - max: per-lane mt + __any() check only; the 2-shfl reduce runs only
//    inside the rare rescale branch (equivalent: max>thr <=> any>thr).
//  - XCD-chunked swizzle clusters the 32 q-blocks of each (b,h) on one
//    XCD -> K/V working set/XCD = 8 heads * 512KB = 4MB ~ L2.
__global__ __launch_bounds__(256)
void attn_kernel(const unsigned short* __restrict__ qb,
                 const unsigned short* __restrict__ kb,
                 const unsigned short* __restrict__ vtb,
                 const int* __restrict__ mask,
                 unsigned short* __restrict__ ctx)
{
  int lane = threadIdx.x & 63, w = threadIdx.x >> 6;
  int lm = lane & 15, lq = lane >> 4;
  int nqb = SEQ / 64;
  // XCD-chunked bijective swizzle (grid = 2048, %8 == 0)
  int nblk = gridDim.x;
  int orig = blockIdx.x;
  int wg = (orig & 7) * (nblk >> 3) + (orig >> 3);
  int qbi = wg % nqb;
  int bh  = wg / nqb;
  int b = bh / NH, hh = bh % NH;
  int q0 = qbi * 64 + w * 16;
  const unsigned short* qp = qb  + (size_t)bh * SEQ * DKH;
  const unsigned short* kp = kb  + (size_t)bh * SEQ * DKH;
  const unsigned short* vp = vtb + (size_t)bh * DKH * SEQ;
  const int* mp = mask + (size_t)b * SEQ;

  bf16x8 aq0 = ld8(qp + (q0 + lm) * DKH + lq*8);
  bf16x8 aq1 = ld8(qp + (q0 + lm) * DKH + lq*8 + 32);

  f32x4 o[4];
#pragma unroll
  for (int j = 0; j < 4; j++) o[j] = (f32x4){0.f, 0.f, 0.f, 0.f};
  float mi = -1e30f, li = 0.f;
  const float scale = 0.125f;   // 1/sqrt(64)

  // one 32-key step, K fragments passed in registers
  auto stepf = [&](bf16x8 k00, bf16x8 k01, bf16x8 k10, bf16x8 k11, int kt) {
    // V loads issued first: consumed only after softmax (~400 cy later)
    bf16x8 vv0 = ld8(vp + ( 0 + lm) * SEQ + kt + lq*8);
    bf16x8 vv1 = ld8(vp + (16 + lm) * SEQ + kt + lq*8);
    bf16x8 vv2 = ld8(vp + (32 + lm) * SEQ + kt + lq*8);
    bf16x8 vv3 = ld8(vp + (48 + lm) * SEQ + kt + lq*8);
    f32x4 s0 = (f32x4){0.f,0.f,0.f,0.f}, s1 = (f32x4){0.f,0.f,0.f,0.f};
    s0 = __builtin_amdgcn_mfma_f32_16x16x32_bf16(k00, aq0, s0, 0, 0, 0);
    s0 = __builtin_amdgcn_mfma_f32_16x16x32_bf16(k01, aq1, s0, 0, 0, 0);
    s1 = __builtin_amdgcn_mfma_f32_16x16x32_bf16(k10, aq0, s1, 0, 0, 0);
    s1 = __builtin_amdgcn_mfma_f32_16x16x32_bf16(k11, aq1, s1, 0, 0, 0);

    int4 m0v = *(const int4*)(mp + kt + lq*4);
    int4 m1v = *(const int4*)(mp + kt + 16 + lq*4);
    int m0a[4] = { m0v.x, m0v.y, m0v.z, m0v.w };
    int m1a[4] = { m1v.x, m1v.y, m1v.z, m1v.w };
    float sv0[4], sv1[4];
#pragma unroll
    for (int r = 0; r < 4; r++) {
      sv0[r] = m0a[r] ? s0[r] * scale : -1e9f;
      sv1[r] = m1a[r] ? s1[r] * scale : -1e9f;
    }
    // per-lane block max (NO cross-lane reduce on the common path)
    float mt = fmaxf(fmaxf(fmaxf(sv0[0], sv0[1]), fmaxf(sv0[2], sv0[3])),
                     fmaxf(fmaxf(sv1[0], sv1[1]), fmaxf(sv1[2], sv1[3])));
    if (__any(mt - mi > 8.0f)) {          // rare: reduce + rescale
      mt = fmaxf(mt, __shfl_xor(mt, 16));
      mt = fmaxf(mt, __shfl_xor(mt, 32));
      float mn = fmaxf(mi, mt);
      float al = __expf(mi - mn);
      mi = mn;
      li *= al;
#pragma unroll
      for (int jt = 0; jt < 4; jt++)
#pragma unroll
        for (int r = 0; r < 4; r++) o[jt][r] *= al;
    }
    float p0[4], p1[4];
#pragma unroll
    for (int r = 0; r < 4; r++) {
      p0[r] = __expf(sv0[r] - mi);
      p1[r] = __expf(sv1[r] - mi);
    }
    // per-lane partial row-sum; reduced once after the loop
    li += (p0[0] + p0[1]) + (p0[2] + p0[3]) + (p1[0] + p1[1]) + (p1[2] + p1[3]);
    // pack and exchange P into B-fragment layout (lane needs P[lm][lq*8..+7])
    uint32_t w0 = pk2(p0[0], p0[1]);
    uint32_t w1 = pk2(p0[2], p0[3]);
    uint32_t w2 = pk2(p1[0], p1[1]);
    uint32_t w3 = pk2(p1[2], p1[3]);
    uint4a pw4;
#pragma unroll
    for (int e = 0; e < 4; e++) {
      int src = lm + (2*(lq & 1) + (e >> 1)) * 16;
      uint32_t tlo = shfl_u32((e & 1) ? w1 : w0, src);
      uint32_t thi = shfl_u32((e & 1) ? w3 : w2, src);
      pw4[e] = (lq < 2) ? tlo : thi;
    }
    bf16x8 pfrag = __builtin_bit_cast(bf16x8, pw4);
    o[0] = __builtin_amdgcn_mfma_f32_16x16x32_bf16(vv0, pfrag, o[0], 0, 0, 0);
    o[1] = __builtin_amdgcn_mfma_f32_16x16x32_bf16(vv1, pfrag, o[1], 0, 0, 0);
    o[2] = __builtin_amdgcn_mfma_f32_16x16x32_bf16(vv2, pfrag, o[2], 0, 0, 0);
    o[3] = __builtin_amdgcn_mfma_f32_16x16x32_bf16(vv3, pfrag, o[3], 0, 0, 0);
  };

  // K prefetch pipeline: named A/B register buffers, unroll-2 (64 keys/iter)
  bf16x8 kA0 = ld8(kp + ( 0 + lm) * DKH + lq*8);
  bf16x8 kA1 = ld8(kp + ( 0 + lm) * DKH + lq*8 + 32);
  bf16x8 kA2 = ld8(kp + (16 + lm) * DKH + lq*8);
  bf16x8 kA3 = ld8(kp + (16 + lm) * DKH + lq*8 + 32);
  for (int kt = 0; kt < SEQ; kt += 64) {
    bf16x8 kB0 = ld8(kp + (kt + 32 + lm) * DKH + lq*8);
    bf16x8 kB1 = ld8(kp + (kt + 32 + lm) * DKH + lq*8 + 32);
    bf16x8 kB2 = ld8(kp + (kt + 48 + lm) * DKH + lq*8);
    bf16x8 kB3 = ld8(kp + (kt + 48 + lm) * DKH + lq*8 + 32);
    stepf(kA0, kA1, kA2, kA3, kt);
    if (kt + 64 < SEQ) {
      kA0 = ld8(kp + (kt + 64 + lm) * DKH + lq*8);
      kA1 = ld8(kp + (kt + 64 + lm) * DKH + lq*8 + 32);
      kA2 = ld8(kp + (kt + 80 + lm) * DKH + lq*8);
      kA3 = ld8(kp + (kt + 80 + lm) * DKH + lq*8 + 32);
    }
    stepf(kB0, kB1, kB2, kB3, kt + 32);
  }
  // final li reduction across the 4 lanes of each q-row
  li += __shfl_xor(li, 16);
  li += __shfl_xor(li, 32);
  float inv = 1.0f / li;
#pragma unroll
  for (int jt = 0; jt < 4; jt++) {
    u16x4 ov;
#pragma unroll
    for (int r = 0; r < 4; r++) ov[r] = f2b(o[jt][r] * inv);
    *(u16x4*)(ctx + (size_t)(b * SEQ + q0 + lm) * D_MODEL + hh*DKH + jt*16 + lq*4) = ov;
  }
}

// ---------------------------------------------------------------- launcher
extern "C" void kernel_launch(void* const* d_in, const int* in_sizes, int n_in,
                              void* d_out, int out_size, void* d_ws, size_t ws_size,
                              hipStream_t stream) {
  const int*   x    = (const int*)d_in[0];
  const int*   mask = (const int*)d_in[1];
  const float* emb  = (const float*)d_in[2];
  const float* wq   = (const float*)d_in[3];
  const float* bq   = (const float*)d_in[4];
  const float* wk   = (const float*)d_in[5];
  const float* bk   = (const float*)d_in[6];
  const float* wv   = (const float*)d_in[7];
  const float* bv   = (const float*)d_in[8];
  const float* wo   = (const float*)d_in[9];
  const float* bo   = (const float*)d_in[10];
  const float* w1   = (const float*)d_in[11];
  const float* b1   = (const float*)d_in[12];
  const float* w2   = (const float*)d_in[13];
  const float* b2   = (const float*)d_in[14];
  const float* g1   = (const float*)d_in[15];
  const float* be1  = (const float*)d_in[16];
  const float* g2   = (const float*)d_in[17];
  const float* be2  = (const float*)d_in[18];
  const float* gf   = (const float*)d_in[19];
  const float* bfin = (const float*)d_in[20];

  const size_t DD = (size_t)D_MODEL * D_MODEL;       // 1M
  const size_t DDF = (size_t)D_MODEL * DFF_N;        // 4M
  char* p = (char*)d_ws;
  auto alloc = [&](size_t bytes) { void* r = (void*)p; p += (bytes + 255) & ~(size_t)255; return r; };
  unsigned short* qkvT = (unsigned short*)alloc(LAYERS * 3 * DD * 2);
  unsigned short* woT  = (unsigned short*)alloc(LAYERS * DD * 2);
  unsigned short* w1T  = (unsigned short*)alloc(LAYERS * DDF * 2);
  unsigned short* w2T  = (unsigned short*)alloc(LAYERS * DDF * 2);
  float*          h    = (float*)alloc((size_t)MROWS * D_MODEL * 4);
  unsigned short* hb   = (unsigned short*)alloc((size_t)MROWS * D_MODEL * 2);
  float*          t0   = (float*)alloc((size_t)MROWS * D_MODEL * 4);
  unsigned short* qB   = (unsigned short*)alloc((size_t)MROWS * D_MODEL * 2);
  unsigned short* kB   = (unsigned short*)alloc((size_t)MROWS * D_MODEL * 2);
  unsigned short* vB   = (unsigned short*)alloc((size_t)MROWS * D_MODEL * 2);
  unsigned short* ctx  = (unsigned short*)alloc((size_t)MROWS * D_MODEL * 2);
  unsigned short* ffa  = qB;   // lifetime-disjoint: reuse q/k/v/ctx region (64MB)

  // ---- weight prep (every call: ws is re-poisoned) ----
  for (int l = 0; l < LAYERS; l++) {
    transpose_cvt<<<dim3(32, 32), 256, 0, stream>>>(wq + l*DD, qkvT + l*3*DD,          D_MODEL, D_MODEL);
    transpose_cvt<<<dim3(32, 32), 256, 0, stream>>>(wk + l*DD, qkvT + l*3*DD + DD,     D_MODEL, D_MODEL);
    transpose_cvt<<<dim3(32, 32), 256, 0, stream>>>(wv + l*DD, qkvT + l*3*DD + 2*DD,   D_MODEL, D_MODEL);
    transpose_cvt<<<dim3(32, 32), 256, 0, stream>>>(wo + l*DD, woT + l*DD,             D_MODEL, D_MODEL);
    transpose_cvt<<<dim3(DFF_N/32, D_MODEL/32), 256, 0, stream>>>(w1 + l*DDF, w1T + l*DDF, D_MODEL, DFF_N);
    transpose_cvt<<<dim3(D_MODEL/32, DFF_N/32), 256, 0, stream>>>(w2 + l*DDF, w2T + l*DDF, DFF_N, D_MODEL);
  }

  embed_kernel<<<MROWS * D_MODEL / 1024, 256, 0, stream>>>(x, emb, h, hb);

  for (int l = 0; l < LAYERS; l++) {
    gemm_bt<GM_QKV><<<dim3(3072/BN, MROWS/BM), 256, 0, stream>>>(
        hb, qkvT + l*3*DD, bq + l*D_MODEL, bk + l*D_MODEL, bv + l*D_MODEL,
        nullptr, nullptr, nullptr, qB, kB, vB, MROWS, 3072, D_MODEL);
    attn_kernel<<<BATCH*NH*(SEQ/64), 256, 0, stream>>>(qB, kB, vB, mask, ctx);
    gemm_bt<GM_ADDRES><<<dim3(D_MODEL/BN, MROWS/BM), 256, 0, stream>>>(
        ctx, woT + l*DD, bo + l*D_MODEL, nullptr, nullptr, h,
        t0, nullptr, nullptr, nullptr, nullptr, MROWS, D_MODEL, D_MODEL);
    ln_kernel<<<MROWS, 256, 0, stream>>>(t0, g1 + l*D_MODEL, be1 + l*D_MODEL, h, hb);
    gemm_bt<GM_RELU><<<dim3(DFF_N/BN, MROWS/BM), 256, 0, stream>>>(
        hb, w1T + l*DDF, b1 + l*DFF_N, nullptr, nullptr, nullptr,
        nullptr, ffa, nullptr, nullptr, nullptr, MROWS, DFF_N, D_MODEL);
    gemm_bt<GM_ADDRES><<<dim3(D_MODEL/BN, MROWS/BM), 256, 0, stream>>>(
        ffa, w2T + l*DDF, b2 + l*D_MODEL, nullptr, nullptr, h,
        t0, nullptr, nullptr, nullptr, nullptr, MROWS, D_MODEL, DFF_N);
    ln_kernel<<<MROWS, 256, 0, stream>>>(t0, g2 + l*D_MODEL, be2 + l*D_MODEL, h, hb);
  }

  ln_kernel<<<MROWS, 256, 0, stream>>>(h, gf, bfin, (float*)d_out, nullptr);
}

// Round 5
// 3599.659 us; speedup vs baseline: 1.5302x; 1.5284x over previous
//
#include <hip/hip_runtime.h>
#include <stdint.h>
#include <stddef.h>

#define D_MODEL 1024
#define NH 16
#define DKH 64
#define SEQ 2048
#define BATCH 4
#define LAYERS 6
#define DFF_N 4096
#define MROWS (BATCH*SEQ)   // 8192 token rows

typedef __attribute__((ext_vector_type(8))) __bf16 bf16x8;
typedef __attribute__((ext_vector_type(4))) float f32x4;
typedef unsigned int uint4a __attribute__((ext_vector_type(4), may_alias, aligned(16)));
typedef __attribute__((ext_vector_type(4))) unsigned short u16x4;

__device__ __forceinline__ unsigned short f2b(float f) {
  union { float f; uint32_t u; } x; x.f = f;
  uint32_t u = x.u + 0x7fffu + ((x.u >> 16) & 1u);   // RNE
  return (unsigned short)(u >> 16);
}

__device__ __forceinline__ uint32_t pk2(float lo, float hi) {
  return (uint32_t)f2b(lo) | ((uint32_t)f2b(hi) << 16);
}

__device__ __forceinline__ uint32_t shfl_u32(uint32_t v, int src) {
  return (uint32_t)__shfl((int)v, src, 64);
}

__device__ __forceinline__ bf16x8 ld8(const unsigned short* p) {
  return __builtin_bit_cast(bf16x8, *(const uint4a*)p);
}

__device__ __forceinline__ void gload_lds16(const unsigned short* g, unsigned short* l) {
  // async 16B/lane global->LDS; LDS dest = wave-uniform base + lane*16
  __builtin_amdgcn_global_load_lds((const __attribute__((address_space(1))) void*)g,
                                   (__attribute__((address_space(3))) void*)l, 16, 0, 0);
}

#define VMCNT2 asm volatile("s_waitcnt vmcnt(2)" ::: "memory")
#define VMCNT0 asm volatile("s_waitcnt vmcnt(0)" ::: "memory")
#define LGKM0  asm volatile("s_waitcnt lgkmcnt(0)" ::: "memory")
#define SBAR() __builtin_amdgcn_s_barrier()

// ---------------------------------------------------------------- transpose+cvt
// dst[c][r] = bf16(src[r][c]); src is R x C f32. grid (C/32, R/32), block 256.
__global__ __launch_bounds__(256)
void transpose_cvt(const float* __restrict__ src, unsigned short* __restrict__ dst,
                   int R, int C)
{
  __shared__ float tile[32][33];
  int tx = threadIdx.x & 31, ty = threadIdx.x >> 5;        // 32 x 8
  int c0 = blockIdx.x * 32, r0 = blockIdx.y * 32;
#pragma unroll
  for (int i = 0; i < 4; i++)
    tile[ty + i*8][tx] = src[(size_t)(r0 + ty + i*8)*C + c0 + tx];
  __syncthreads();
#pragma unroll
  for (int i = 0; i < 4; i++)
    dst[(size_t)(c0 + ty + i*8)*R + r0 + tx] = f2b(tile[tx][ty + i*8]);
}

// ---------------------------------------------------------------- embed + PE
__global__ __launch_bounds__(256)
void embed_kernel(const int* __restrict__ x, const float* __restrict__ emb,
                  float* __restrict__ h, unsigned short* __restrict__ hb)
{
  size_t q = (size_t)blockIdx.x * 256 + threadIdx.x;       // over MROWS*D/4
  size_t e0 = q << 2;
  int d0 = (int)(e0 & (D_MODEL - 1));
  size_t bs = e0 >> 10;
  int s = (int)(bs & (SEQ - 1));
  int tok = x[bs];
  const float4 ev = *(const float4*)(emb + (size_t)tok * D_MODEL + d0);
  int i0 = d0 >> 1;
  float div0 = __expf(-0.017988946039016f * (float)i0);        // exp(2i*-ln(1e4)/1024)
  float div1 = __expf(-0.017988946039016f * (float)(i0 + 1));
  float a0 = (float)s * div0, a1 = (float)s * div1;
  float4 o;
  o.x = ev.x * 32.0f + __sinf(a0);                             // sqrt(1024)=32
  o.y = ev.y * 32.0f + __cosf(a0);
  o.z = ev.z * 32.0f + __sinf(a1);
  o.w = ev.w * 32.0f + __cosf(a1);
  *(float4*)(h + e0) = o;
  u16x4 ob = { f2b(o.x), f2b(o.y), f2b(o.z), f2b(o.w) };
  *(u16x4*)(hb + e0) = ob;
}

// ---------------------------------------------------------------- LayerNorm
__global__ __launch_bounds__(256)
void ln_kernel(const float* __restrict__ in, const float* __restrict__ g,
               const float* __restrict__ be, float* __restrict__ outf,
               unsigned short* __restrict__ outb)
{
  int row = blockIdx.x;
  int t = threadIdx.x, lane = t & 63, w = t >> 6;
  float4 v = *(const float4*)(in + (size_t)row * D_MODEL + t*4);
  float s = v.x + v.y + v.z + v.w;
#pragma unroll
  for (int off = 1; off < 64; off <<= 1) s += __shfl_xor(s, off);
  __shared__ float redA[4], redB[4];
  if (lane == 0) redA[w] = s;
  __syncthreads();
  float mu = (redA[0] + redA[1] + redA[2] + redA[3]) * (1.0f / D_MODEL);
  float dx = v.x - mu, dy = v.y - mu, dz = v.z - mu, dw = v.w - mu;
  float q = dx*dx + dy*dy + dz*dz + dw*dw;
#pragma unroll
  for (int off = 1; off < 64; off <<= 1) q += __shfl_xor(q, off);
  if (lane == 0) redB[w] = q;
  __syncthreads();
  float var = (redB[0] + redB[1] + redB[2] + redB[3]) * (1.0f / D_MODEL);
  float rs = rsqrtf(var + 1e-5f);
  float4 gv = *(const float4*)(g + t*4);
  float4 bv = *(const float4*)(be + t*4);
  float4 o;
  o.x = dx * rs * gv.x + bv.x;
  o.y = dy * rs * gv.y + bv.y;
  o.z = dz * rs * gv.z + bv.z;
  o.w = dw * rs * gv.w + bv.w;
  *(float4*)(outf + (size_t)row * D_MODEL + t*4) = o;
  if (outb) {
    u16x4 ob = { f2b(o.x), f2b(o.y), f2b(o.z), f2b(o.w) };
    *(u16x4*)(outb + (size_t)row * D_MODEL + t*4) = ob;
  }
}

// ---------------------------------------------------------------- GEMM (B^T form)
#define BM 128
#define BN 128
#define BKT 32

#define GM_QKV 0
#define GM_ADDRES 1
#define GM_RELU 2

template<int MODE>
__global__ __launch_bounds__(256)
void gemm_bt(const unsigned short* __restrict__ A,
             const unsigned short* __restrict__ Bt,
             const float* __restrict__ bias0, const float* __restrict__ bias1,
             const float* __restrict__ bias2, const float* __restrict__ resid,
             float* __restrict__ outf, unsigned short* __restrict__ outb,
             unsigned short* __restrict__ qo, unsigned short* __restrict__ ko,
             unsigned short* __restrict__ vo,
             int M, int N, int K)
{
  __shared__ __align__(16) unsigned short sA[BM * BKT];
  __shared__ __align__(16) unsigned short sB[BN * BKT];
  int tid = threadIdx.x;
  int w = tid >> 6, lane = tid & 63;
  int lm = lane & 15, lq = lane >> 4;
  int wm = w & 1, wn = w >> 1;

  // T1: XCD k (= orig%8) processes contiguous chunk of the grid
  int nwg  = gridDim.x * gridDim.y;
  int orig = blockIdx.y * gridDim.x + blockIdx.x;
  int nx   = nwg >> 3;
  int wg   = (orig & 7) * nx + (orig >> 3);
  int bx   = wg % gridDim.x, by = wg / gridDim.x;
  int n0 = bx * BN, m0 = by * BM;

  f32x4 acc[4][4];
#pragma unroll
  for (int i = 0; i < 4; i++)
#pragma unroll
    for (int j = 0; j < 4; j++) acc[i][j] = (f32x4){0.f, 0.f, 0.f, 0.f};

  int srow = lane >> 2;               // 0..15
  int scol = (lane & 3) * 8;          // element offset in K
  const unsigned short* ga0 = A  + (size_t)(m0 + w*32 + srow) * K + scol;
  const unsigned short* ga1 = ga0 + (size_t)16 * K;
  const unsigned short* gb0 = Bt + (size_t)(n0 + w*32 + srow) * K + scol;
  const unsigned short* gb1 = gb0 + (size_t)16 * K;
  unsigned short* la0 = &sA[(w*32 +  0) * BKT];
  unsigned short* la1 = &sA[(w*32 + 16) * BKT];
  unsigned short* lb0 = &sB[(w*32 +  0) * BKT];
  unsigned short* lb1 = &sB[(w*32 + 16) * BKT];

  for (int kt = 0; kt < K; kt += BKT) {
    gload_lds16(ga0 + kt, la0);
    gload_lds16(ga1 + kt, la1);
    gload_lds16(gb0 + kt, lb0);
    gload_lds16(gb1 + kt, lb1);
    __syncthreads();
    bf16x8 af[4], bfr[4];
#pragma unroll
    for (int i = 0; i < 4; i++)
      af[i] = ld8(&sA[(wm*64 + i*16 + lm) * BKT + lq*8]);
#pragma unroll
    for (int j = 0; j < 4; j++)
      bfr[j] = ld8(&sB[(wn*64 + j*16 + lm) * BKT + lq*8]);
#pragma unroll
    for (int i = 0; i < 4; i++)
#pragma unroll
      for (int j = 0; j < 4; j++)
        acc[i][j] = __builtin_amdgcn_mfma_f32_16x16x32_bf16(af[i], bfr[j], acc[i][j], 0, 0, 0);
    __syncthreads();
  }

  // epilogue: C row = (lane>>4)*4 + r, col = lane&15 (verified m89/m91)
#pragma unroll
  for (int i = 0; i < 4; i++) {
#pragma unroll
    for (int j = 0; j < 4; j++) {
      int n = n0 + wn*64 + j*16 + lm;
#pragma unroll
      for (int r = 0; r < 4; r++) {
        int m = m0 + wm*64 + i*16 + lq*4 + r;
        float val = acc[i][j][r];
        if constexpr (MODE == GM_QKV) {
          int which = n >> 10, nn = n & 1023;
          const float* bb = (which == 0) ? bias0 : (which == 1) ? bias1 : bias2;
          val += bb[nn];
          int hh = nn >> 6, dk = nn & 63;
          int b = m >> 11, s = m & 2047;
          size_t bh = (size_t)(b * NH + hh);
          if (which == 0)      qo[(bh * SEQ + s) * DKH + dk] = f2b(val);
          else if (which == 1) ko[(bh * SEQ + s) * DKH + dk] = f2b(val);
          else                 vo[(bh * DKH + dk) * SEQ + s] = f2b(val);   // V transposed
        } else if constexpr (MODE == GM_ADDRES) {
          val += bias0[n] + resid[(size_t)m * N + n];
          outf[(size_t)m * N + n] = val;
        } else {  // GM_RELU
          val += bias0[n];
          val = fmaxf(val, 0.f);
          outb[(size_t)m * N + n] = f2b(val);
        }
      }
    }
  }
}

// ---------------------------------------------------------------- flash attention
// K/V staged in LDS ONCE per block per 32-key step (waves 0-1 stage K, 2-3 stage
// V; 2 global_load_lds each), double-buffered with counted vmcnt(2) + raw
// s_barrier (loads stay in flight across barriers). XOR-swizzled LDS layout
// (rule #21: inverse swizzle on the per-lane GLOBAL source, linear LDS dest,
// swizzle on the ds_read):
//   K tile 32 rows x 128B: byte(r,c) = r*128 + (c ^ (r&7))*16
//   V tile 64 rows x  64B: byte(r,c) = r*64  + (c ^ ((r>>1)&3))*16
// Mask is preloaded to an LDS f32 bias table (0 / -1e9) so the in-loop VMEM
// stream is EXACTLY 2 gloads/wave/phase (vmcnt bookkeeping sound).
// Softmax: swapped-operand per-lane-scalar state; P-exchange via 8 bpermute;
// PV O^T = mfma(V^T, P). Same math as round 4 (HW-verified, absmax 0.03125).
__global__ __launch_bounds__(256)
void attn_kernel(const unsigned short* __restrict__ qb,
                 const unsigned short* __restrict__ kb,
                 const unsigned short* __restrict__ vtb,
                 const int* __restrict__ mask,
                 unsigned short* __restrict__ ctx)
{
  __shared__ __align__(16) unsigned short sK[2][2048];   // 2 x 4KB
  __shared__ __align__(16) unsigned short sV[2][2048];   // 2 x 4KB
  __shared__ __align__(16) float sBias[SEQ];             // 8KB

  int tid = threadIdx.x;
  int lane = tid & 63, wv = tid >> 6;
  int lm = lane & 15, lq = lane >> 4;
  int nqb = SEQ / 64;
  // XCD-chunked bijective swizzle (grid = 2048, %8 == 0)
  int nblk = gridDim.x;
  int orig = blockIdx.x;
  int wg = (orig & 7) * (nblk >> 3) + (orig >> 3);
  int qbi = wg % nqb;
  int bh  = wg / nqb;
  int b = bh / NH, hh = bh % NH;
  int q0 = qbi * 64 + wv * 16;
  const unsigned short* qp = qb  + (size_t)bh * SEQ * DKH;
  const unsigned short* kp = kb  + (size_t)bh * SEQ * DKH;
  const unsigned short* vp = vtb + (size_t)bh * DKH * SEQ;
  const int* mp = mask + (size_t)b * SEQ;

  // mask -> additive f32 bias in LDS (once per block)
  for (int j = tid; j < SEQ; j += 256)
    sBias[j] = mp[j] ? 0.0f : -1e9f;
  __syncthreads();

  bf16x8 aq0 = ld8(qp + (q0 + lm) * DKH + lq*8);
  bf16x8 aq1 = ld8(qp + (q0 + lm) * DKH + lq*8 + 32);

  f32x4 o[4];
#pragma unroll
  for (int j = 0; j < 4; j++) o[j] = (f32x4){0.f, 0.f, 0.f, 0.f};
  float mi = -1e30f, li = 0.f;
  const float scale = 0.125f;   // 1/sqrt(64)

  // ---- stage: 2 gloads per wave (uniform across waves for vmcnt counting)
  int krow = (lane >> 3);                 // K: sub-row within 8-row group
  int kchk = (lane & 7) ^ (lane >> 3);    // K: global chunk for linear slot
  int vrow = (lane >> 2);                 // V: sub-row within 16-row group
  int vchk = (lane & 3) ^ ((lane >> 3) & 3);
  auto STAGE = [&](int buf, int kt) {
    if (wv < 2) {
      int r = wv*16 + krow;
      gload_lds16(kp + (size_t)(kt + r    ) * DKH + kchk*8, &sK[buf][wv*1024 +   0]);
      gload_lds16(kp + (size_t)(kt + r + 8) * DKH + kchk*8, &sK[buf][wv*1024 + 512]);
    } else {
      int r = (wv-2)*32 + vrow;
      gload_lds16(vp + (size_t)(r     ) * SEQ + kt + vchk*8, &sV[buf][(wv-2)*1024 +   0]);
      gload_lds16(vp + (size_t)(r + 16) * SEQ + kt + vchk*8, &sV[buf][(wv-2)*1024 + 512]);
    }
  };

  // ---- swizzled read offsets (ushort indices)
  int ks0 = ((lq    ) ^ (lm & 7)) * 8;
  int ks1 = ((lq + 4) ^ (lm & 7)) * 8;
  int vs  = (lq ^ ((lm >> 1) & 3)) * 8;

  auto COMPUTE = [&](bf16x8 k00, bf16x8 k01, bf16x8 k10, bf16x8 k11,
                     bf16x8 vv0, bf16x8 vv1, bf16x8 vv2, bf16x8 vv3,
                     f32x4 b0, f32x4 b1) {
    f32x4 s0 = (f32x4){0.f,0.f,0.f,0.f}, s1 = (f32x4){0.f,0.f,0.f,0.f};
    s0 = __builtin_amdgcn_mfma_f32_16x16x32_bf16(k00, aq0, s0, 0, 0, 0);
    s0 = __builtin_amdgcn_mfma_f32_16x16x32_bf16(k01, aq1, s0, 0, 0, 0);
    s1 = __builtin_amdgcn_mfma_f32_16x16x32_bf16(k10, aq0, s1, 0, 0, 0);
    s1 = __builtin_amdgcn_mfma_f32_16x16x32_bf16(k11, aq1, s1, 0, 0, 0);
    float sv0[4], sv1[4];
#pragma unroll
    for (int r = 0; r < 4; r++) {
      sv0[r] = s0[r] * scale + b0[r];
      sv1[r] = s1[r] * scale + b1[r];
    }
    float mt = fmaxf(fmaxf(fmaxf(sv0[0], sv0[1]), fmaxf(sv0[2], sv0[3])),
                     fmaxf(fmaxf(sv1[0], sv1[1]), fmaxf(sv1[2], sv1[3])));
    if (__any(mt - mi > 8.0f)) {          // rare: reduce + rescale
      mt = fmaxf(mt, __shfl_xor(mt, 16));
      mt = fmaxf(mt, __shfl_xor(mt, 32));
      float mn = fmaxf(mi, mt);
      float al = __expf(mi - mn);
      mi = mn;
      li *= al;
#pragma unroll
      for (int jt = 0; jt < 4; jt++)
#pragma unroll
        for (int r = 0; r < 4; r++) o[jt][r] *= al;
    }
    float p0[4], p1[4];
#pragma unroll
    for (int r = 0; r < 4; r++) {
      p0[r] = __expf(sv0[r] - mi);
      p1[r] = __expf(sv1[r] - mi);
    }
    li += (p0[0] + p0[1]) + (p0[2] + p0[3]) + (p1[0] + p1[1]) + (p1[2] + p1[3]);
    uint32_t w0 = pk2(p0[0], p0[1]);
    uint32_t w1 = pk2(p0[2], p0[3]);
    uint32_t w2 = pk2(p1[0], p1[1]);
    uint32_t w3 = pk2(p1[2], p1[3]);
    uint4a pw4;
#pragma unroll
    for (int e = 0; e < 4; e++) {
      int src = lm + (2*(lq & 1) + (e >> 1)) * 16;
      uint32_t tlo = shfl_u32((e & 1) ? w1 : w0, src);
      uint32_t thi = shfl_u32((e & 1) ? w3 : w2, src);
      pw4[e] = (lq < 2) ? tlo : thi;
    }
    bf16x8 pfrag = __builtin_bit_cast(bf16x8, pw4);
    o[0] = __builtin_amdgcn_mfma_f32_16x16x32_bf16(vv0, pfrag, o[0], 0, 0, 0);
    o[1] = __builtin_amdgcn_mfma_f32_16x16x32_bf16(vv1, pfrag, o[1], 0, 0, 0);
    o[2] = __builtin_amdgcn_mfma_f32_16x16x32_bf16(vv2, pfrag, o[2], 0, 0, 0);
    o[3] = __builtin_amdgcn_mfma_f32_16x16x32_bf16(vv3, pfrag, o[3], 0, 0, 0);
  };

  // ---- pipelined loop: 64 steps, unroll x2 (buf0 / buf1 static)
  STAGE(0, 0);
  for (int tt = 0; tt < 64; tt += 2) {
    int kt0 = tt * 32;
    // even phase: stage buf1(kt0+32), consume buf0(kt0)
    STAGE(1, kt0 + 32);
    VMCNT2; SBAR();
    {
      bf16x8 k00 = ld8(&sK[0][lm*64        + ks0]);
      bf16x8 k01 = ld8(&sK[0][lm*64        + ks1]);
      bf16x8 k10 = ld8(&sK[0][lm*64 + 1024 + ks0]);
      bf16x8 k11 = ld8(&sK[0][lm*64 + 1024 + ks1]);
      bf16x8 vv0 = ld8(&sV[0][        lm*32 + vs]);
      bf16x8 vv1 = ld8(&sV[0][ 512 +  lm*32 + vs]);
      bf16x8 vv2 = ld8(&sV[0][1024 +  lm*32 + vs]);
      bf16x8 vv3 = ld8(&sV[0][1536 +  lm*32 + vs]);
      f32x4 b0 = *(const f32x4*)&sBias[kt0 + lq*4];
      f32x4 b1 = *(const f32x4*)&sBias[kt0 + 16 + lq*4];
      LGKM0; SBAR();
      COMPUTE(k00, k01, k10, k11, vv0, vv1, vv2, vv3, b0, b1);
    }
    // odd phase: stage buf0(kt0+64) if any, consume buf1(kt0+32)
    if (tt + 2 < 64) { STAGE(0, kt0 + 64); VMCNT2; }
    else             { VMCNT0; }
    SBAR();
    {
      bf16x8 k00 = ld8(&sK[1][lm*64        + ks0]);
      bf16x8 k01 = ld8(&sK[1][lm*64        + ks1]);
      bf16x8 k10 = ld8(&sK[1][lm*64 + 1024 + ks0]);
      bf16x8 k11 = ld8(&sK[1][lm*64 + 1024 + ks1]);
      bf16x8 vv0 = ld8(&sV[1][        lm*32 + vs]);
      bf16x8 vv1 = ld8(&sV[1][ 512 +  lm*32 + vs]);
      bf16x8 vv2 = ld8(&sV[1][1024 +  lm*32 + vs]);
      bf16x8 vv3 = ld8(&sV[1][1536 +  lm*32 + vs]);
      f32x4 b0 = *(const f32x4*)&sBias[kt0 + 32 + lq*4];
      f32x4 b1 = *(const f32x4*)&sBias[kt0 + 48 + lq*4];
      LGKM0; SBAR();
      COMPUTE(k00, k01, k10, k11, vv0, vv1, vv2, vv3, b0, b1);
    }
  }
  // final li reduction across the 4 lanes of each q-row
  li += __shfl_xor(li, 16);
  li += __shfl_xor(li, 32);
  float inv = 1.0f / li;
#pragma unroll
  for (int jt = 0; jt < 4; jt++) {
    u16x4 ov;
#pragma unroll
    for (int r = 0; r < 4; r++) ov[r] = f2b(o[jt][r] * inv);
    *(u16x4*)(ctx + (size_t)(b * SEQ + q0 + lm) * D_MODEL + hh*DKH + jt*16 + lq*4) = ov;
  }
}

// ---------------------------------------------------------------- launcher
extern "C" void kernel_launch(void* const* d_in, const int* in_sizes, int n_in,
                              void* d_out, int out_size, void* d_ws, size_t ws_size,
                              hipStream_t stream) {
  const int*   x    = (const int*)d_in[0];
  const int*   mask = (const int*)d_in[1];
  const float* emb  = (const float*)d_in[2];
  const float* wq   = (const float*)d_in[3];
  const float* bq   = (const float*)d_in[4];
  const float* wk   = (const float*)d_in[5];
  const float* bk   = (const float*)d_in[6];
  const float* wv   = (const float*)d_in[7];
  const float* bv   = (const float*)d_in[8];
  const float* wo   = (const float*)d_in[9];
  const float* bo   = (const float*)d_in[10];
  const float* w1   = (const float*)d_in[11];
  const float* b1   = (const float*)d_in[12];
  const float* w2   = (const float*)d_in[13];
  const float* b2   = (const float*)d_in[14];
  const float* g1   = (const float*)d_in[15];
  const float* be1  = (const float*)d_in[16];
  const float* g2   = (const float*)d_in[17];
  const float* be2  = (const float*)d_in[18];
  const float* gf   = (const float*)d_in[19];
  const float* bfin = (const float*)d_in[20];

  const size_t DD = (size_t)D_MODEL * D_MODEL;       // 1M
  const size_t DDF = (size_t)D_MODEL * DFF_N;        // 4M
  char* p = (char*)d_ws;
  auto alloc = [&](size_t bytes) { void* r = (void*)p; p += (bytes + 255) & ~(size_t)255; return r; };
  unsigned short* qkvT = (unsigned short*)alloc(LAYERS * 3 * DD * 2);
  unsigned short* woT  = (unsigned short*)alloc(LAYERS * DD * 2);
  unsigned short* w1T  = (unsigned short*)alloc(LAYERS * DDF * 2);
  unsigned short* w2T  = (unsigned short*)alloc(LAYERS * DDF * 2);
  float*          h    = (float*)alloc((size_t)MROWS * D_MODEL * 4);
  unsigned short* hb   = (unsigned short*)alloc((size_t)MROWS * D_MODEL * 2);
  float*          t0   = (float*)alloc((size_t)MROWS * D_MODEL * 4);
  unsigned short* qB   = (unsigned short*)alloc((size_t)MROWS * D_MODEL * 2);
  unsigned short* kB   = (unsigned short*)alloc((size_t)MROWS * D_MODEL * 2);
  unsigned short* vB   = (unsigned short*)alloc((size_t)MROWS * D_MODEL * 2);
  unsigned short* ctx  = (unsigned short*)alloc((size_t)MROWS * D_MODEL * 2);
  unsigned short* ffa  = qB;   // lifetime-disjoint: reuse q/k/v/ctx region (64MB)

  // ---- weight prep (every call: ws is re-poisoned) ----
  for (int l = 0; l < LAYERS; l++) {
    transpose_cvt<<<dim3(32, 32), 256, 0, stream>>>(wq + l*DD, qkvT + l*3*DD,          D_MODEL, D_MODEL);
    transpose_cvt<<<dim3(32, 32), 256, 0, stream>>>(wk + l*DD, qkvT + l*3*DD + DD,     D_MODEL, D_MODEL);
    transpose_cvt<<<dim3(32, 32), 256, 0, stream>>>(wv + l*DD, qkvT + l*3*DD + 2*DD,   D_MODEL, D_MODEL);
    transpose_cvt<<<dim3(32, 32), 256, 0, stream>>>(wo + l*DD, woT + l*DD,             D_MODEL, D_MODEL);
    transpose_cvt<<<dim3(DFF_N/32, D_MODEL/32), 256, 0, stream>>>(w1 + l*DDF, w1T + l*DDF, D_MODEL, DFF_N);
    transpose_cvt<<<dim3(D_MODEL/32, DFF_N/32), 256, 0, stream>>>(w2 + l*DDF, w2T + l*DDF, DFF_N, D_MODEL);
  }

  embed_kernel<<<MROWS * D_MODEL / 1024, 256, 0, stream>>>(x, emb, h, hb);

  for (int l = 0; l < LAYERS; l++) {
    gemm_bt<GM_QKV><<<dim3(3072/BN, MROWS/BM), 256, 0, stream>>>(
        hb, qkvT + l*3*DD, bq + l*D_MODEL, bk + l*D_MODEL, bv + l*D_MODEL,
        nullptr, nullptr, nullptr, qB, kB, vB, MROWS, 3072, D_MODEL);
    attn_kernel<<<BATCH*NH*(SEQ/64), 256, 0, stream>>>(qB, kB, vB, mask, ctx);
    gemm_bt<GM_ADDRES><<<dim3(D_MODEL/BN, MROWS/BM), 256, 0, stream>>>(
        ctx, woT + l*DD, bo + l*D_MODEL, nullptr, nullptr, h,
        t0, nullptr, nullptr, nullptr, nullptr, MROWS, D_MODEL, D_MODEL);
    ln_kernel<<<MROWS, 256, 0, stream>>>(t0, g1 + l*D_MODEL, be1 + l*D_MODEL, h, hb);
    gemm_bt<GM_RELU><<<dim3(DFF_N/BN, MROWS/BM), 256, 0, stream>>>(
        hb, w1T + l*DDF, b1 + l*DFF_N, nullptr, nullptr, nullptr,
        nullptr, ffa, nullptr, nullptr, nullptr, MROWS, DFF_N, D_MODEL);
    gemm_bt<GM_ADDRES><<<dim3(D_MODEL/BN, MROWS/BM), 256, 0, stream>>>(
        ffa, w2T + l*DDF, b2 + l*D_MODEL, nullptr, nullptr, h,
        t0, nullptr, nullptr, nullptr, nullptr, MROWS, D_MODEL, DFF_N);
    ln_kernel<<<MROWS, 256, 0, stream>>>(t0, g2 + l*D_MODEL, be2 + l*D_MODEL, h, hb);
  }

  ln_kernel<<<MROWS, 256, 0, stream>>>(h, gf, bfin, (float*)d_out, nullptr);
}